// Round 6
// baseline (915.118 us; speedup 1.0000x reference)
//
#include <hip/hip_runtime.h>

#define N_NODES 100000
#define N_EDGES 6400000
#define IN_CH   128
#define HID     32

#define BKT_SHIFT 9
#define BKT_MASK  511
#define BKT_SZ    512
#define NBKT      196           // ceil(100000/512)
#define NBLK      1024          // histogram/scatter tiles
#define TILE      6250          // 6.4M / 1024 exactly
#define NCHUNK    4
#define CBASE     25000         // nodes per source chunk (3.2 MB of features)

// ---------- ws layout (bytes) ----------
// region A [0, 25.6M): ebuf during build; then hs | hs2 after k_sort2
#define O_EBUF 0u
#define O_HS   0u
#define O_HS2  12800000u
// region B: ghist+cursors during build; csr16 (12.8MB) overlays after scatter
#define O_GH   25600000u        // 1024*196*4 = 802,816
#define O_CUR  26402816u        // 802,816 (dead after k_scatter)
#define O_CSR  25600000u        // ushort[6.4M] = 12,800,000 -> ends 38.4M
// small persistent region
#define O_ROWS4 38400000u       // int[100000][4] = 1,600,000 (node-major, int4/node)
#define O_CNT4  40000000u       // int[100000][4] = 1,600,000
#define O_DINV  41600000u       // 400,000
#define O_BST   42000000u       // (NBKT+1)*4
#define O_BTOT  42002048u       // NBKT*4
#define O_FLAG  42004096u       // 4

// Detect whether edge_index buffer is int64 (high words all zero) or int32.
__global__ void k_detect(const unsigned int* e, int* flag) {
    __shared__ int any;
    if (threadIdx.x == 0) any = 0;
    __syncthreads();
    int acc = 0;
    for (int i = threadIdx.x; i < 4096; i += 256)
        acc |= (e[2 * i + 1] != 0u);
    if (acc) atomicOr(&any, 1);
    __syncthreads();
    if (threadIdx.x == 0) *flag = any ? 0 : 1;   // 1 => int64
}

// Non-temporal streaming edge load (no L2 pollution).
__device__ __forceinline__ int eload_nt(const int* e, int is64, long long idx) {
    return is64 ? (int)__builtin_nontemporal_load((const long long*)e + idx)
                : __builtin_nontemporal_load(e + (size_t)idx);
}

// Per-tile histogram over destination buckets (LDS int atomics only).
__global__ void k_hist(const int* e, const int* flag, int* ghist) {
    __shared__ int h[NBKT];
    for (int i = threadIdx.x; i < NBKT; i += 256) h[i] = 0;
    __syncthreads();
    int is64 = *flag;
    long long base = (long long)blockIdx.x * TILE;
    for (int k = threadIdx.x; k < TILE; k += 256) {
        int dst = eload_nt(e, is64, (long long)N_EDGES + base + k);
        atomicAdd(&h[dst >> BKT_SHIFT], 1);
    }
    __syncthreads();
    int* g = ghist + blockIdx.x * NBKT;
    for (int i = threadIdx.x; i < NBKT; i += 256) g[i] = h[i];
}

__global__ void k_scan1(const int* __restrict__ ghist, int* __restrict__ btot) {
    int j = blockIdx.x * 256 + threadIdx.x;
    if (j >= NBKT) return;
    int t = 0;
    for (int blk = 0; blk < NBLK; ++blk) t += ghist[blk * NBKT + j];
    btot[j] = t;
}

__global__ void k_scan2(const int* __restrict__ btot, int* __restrict__ bstart) {
    __shared__ int s[1024];
    int t = threadIdx.x;
    int v = (t < NBKT) ? btot[t] : 0;
    s[t] = v;
    __syncthreads();
    for (int off = 1; off < 1024; off <<= 1) {
        int u = (t >= off) ? s[t - off] : 0;
        __syncthreads();
        s[t] += u;
        __syncthreads();
    }
    if (t < NBKT) bstart[t] = s[t] - v;
    if (t == 0) bstart[NBKT] = N_EDGES;
}

__global__ void k_scan3(const int* __restrict__ ghist, const int* __restrict__ bstart,
                        int* __restrict__ cursors) {
    int j = blockIdx.x * 256 + threadIdx.x;
    if (j >= NBKT) return;
    int run = bstart[j];
    for (int blk = 0; blk < NBLK; ++blk) {
        cursors[blk * NBKT + j] = run;
        run += ghist[blk * NBKT + j];
    }
}

// Scatter edges into dst-bucket-grouped ebuf; packed (src<<9)|(dst&511).
// nt loads (streaming) + nt stores (partial-line writes merge in LLC, not L2).
__global__ void k_scatter(const int* e, const int* flag, const int* __restrict__ cursors,
                          unsigned int* __restrict__ ebuf) {
    __shared__ int cur[NBKT];
    const int* c = cursors + blockIdx.x * NBKT;
    for (int i = threadIdx.x; i < NBKT; i += 256) cur[i] = c[i];
    __syncthreads();
    int is64 = *flag;
    long long base = (long long)blockIdx.x * TILE;
    for (int k = threadIdx.x; k < TILE; k += 256) {
        int src = eload_nt(e, is64, base + k);
        int dst = eload_nt(e, is64, (long long)N_EDGES + base + k);
        int pos = atomicAdd(&cur[dst >> BKT_SHIFT], 1);
        unsigned v = ((unsigned)src << BKT_SHIFT) | (unsigned)(dst & BKT_MASK);
        __builtin_nontemporal_store(v, &ebuf[pos]);
    }
}

// Per-bucket counting sort by (src_chunk, dst_local): 2048 bins.
// Emits csr16 (chunk-local src ids), node-major rows4/cnt4, dinv.
__launch_bounds__(512)
__global__ void k_sort2(const unsigned int* __restrict__ ebuf, const int* __restrict__ bstart,
                        unsigned short* __restrict__ csr16, int* __restrict__ rows4,
                        int* __restrict__ cnt4, float* __restrict__ dinv) {
    __shared__ int hist[NCHUNK * BKT_SZ];   // 8 KB
    __shared__ int cur[NCHUNK * BKT_SZ];    // 8 KB
    __shared__ int wsum[8];
    int b = blockIdx.x;
    int s0 = bstart[b], e0 = bstart[b + 1];
    int t = threadIdx.x;
#pragma unroll
    for (int i = 0; i < NCHUNK; ++i) hist[i * 512 + t] = 0;
    __syncthreads();
    for (int i = s0 + t; i < e0; i += 512) {
        unsigned v = __builtin_nontemporal_load(&ebuf[i]);
        int src = (int)(v >> BKT_SHIFT);
        int c = src / CBASE;
        atomicAdd(&hist[c * 512 + (v & BKT_MASK)], 1);
    }
    __syncthreads();
    // block-wide exclusive scan over 2048 bins; thread t owns bins 4t..4t+3
    int c0 = hist[4 * t + 0], c1 = hist[4 * t + 1], c2 = hist[4 * t + 2], c3 = hist[4 * t + 3];
    int ssum = c0 + c1 + c2 + c3;
    {
        int lane = t & 63, w = t >> 6;
        int p = ssum;
#pragma unroll
        for (int off = 1; off < 64; off <<= 1) {
            int u = __shfl_up(p, off, 64);
            if (lane >= off) p += u;
        }
        if (lane == 63) wsum[w] = p;
        __syncthreads();
        int woff = 0;
        for (int k = 0; k < w; ++k) woff += wsum[k];
        int excl = woff + p - ssum;
        int e0b = s0 + excl;
        int e1b = e0b + c0, e2b = e1b + c1, e3b = e2b + c2;
        cur[4 * t + 0] = e0b; cur[4 * t + 1] = e1b;
        cur[4 * t + 2] = e2b; cur[4 * t + 3] = e3b;
        int starts[4] = {e0b, e1b, e2b, e3b};
        int cnts[4]   = {c0, c1, c2, c3};
#pragma unroll
        for (int i = 0; i < 4; ++i) {
            int bin = 4 * t + i;
            int c = bin >> 9, dl = bin & BKT_MASK;
            int node = b * BKT_SZ + dl;
            if (node < N_NODES) {
                rows4[node * 4 + c] = starts[i];     // node-major for int4 load
                cnt4[node * 4 + c]  = cnts[i];
            }
        }
    }
    __syncthreads();
    {
        int node = b * BKT_SZ + t;
        if (node < N_NODES) {
            int deg = hist[t] + hist[512 + t] + hist[1024 + t] + hist[1536 + t];
            dinv[node] = rsqrtf((float)(deg + 1));
        }
    }
    for (int i = s0 + t; i < e0; i += 512) {
        unsigned v = __builtin_nontemporal_load(&ebuf[i]);
        int src = (int)(v >> BKT_SHIFT);
        int c = src / CBASE;
        int pos = atomicAdd(&cur[c * 512 + (v & BKT_MASK)], 1);
        __builtin_nontemporal_store((unsigned short)(src - c * CBASE), &csr16[pos]);
    }
}

// hs[i][c] = dinv[i] * sum_k x[i][k] * W1[k][c]
__launch_bounds__(256)
__global__ void k_gemm1(const float* __restrict__ x, const float* __restrict__ W1,
                        const float* __restrict__ dinv, float* __restrict__ hs) {
    __shared__ float w[IN_CH * HID];
    __shared__ float xs[8 * IN_CH];
    for (int i = threadIdx.x; i < IN_CH * HID; i += 256) w[i] = W1[i];
    const float4* xb = (const float4*)(x + (size_t)blockIdx.x * 8 * IN_CH);
    ((float4*)xs)[threadIdx.x] = xb[threadIdx.x];
    __syncthreads();
    int lane = threadIdx.x & 31, hw = threadIdx.x >> 5;
    int node = blockIdx.x * 8 + hw;
    const float* xr = xs + hw * IN_CH;
    float acc = 0.f;
#pragma unroll
    for (int k = 0; k < IN_CH; ++k) acc += xr[k] * w[k * HID + lane];
    hs[(size_t)node * HID + lane] = acc * dinv[node];
}

// Register-resident 4-chunk gather loop (shared by both aggs).
__device__ __forceinline__ float agg_chunks(const float* __restrict__ feat,
                                            const unsigned short* __restrict__ csr16,
                                            const int* __restrict__ rows4,
                                            const int* __restrict__ cnt4,
                                            int node, int lane, float acc) {
    int4 rs = ((const int4*)rows4)[node];
    int4 cn = ((const int4*)cnt4)[node];
    int starts[4] = {rs.x, rs.y, rs.z, rs.w};
    int lens[4]   = {cn.x, cn.y, cn.z, cn.w};
#pragma unroll
    for (int c = 0; c < NCHUNK; ++c) {
        const unsigned short* cs = csr16 + starts[c];
        const float* fb = feat + (size_t)(c * CBASE) * HID;
        int len = lens[c];
        int j = 0;
        for (; j + 8 <= len; j += 8) {
            int t0 = __builtin_nontemporal_load(cs + j + 0);
            int t1 = __builtin_nontemporal_load(cs + j + 1);
            int t2 = __builtin_nontemporal_load(cs + j + 2);
            int t3 = __builtin_nontemporal_load(cs + j + 3);
            int t4 = __builtin_nontemporal_load(cs + j + 4);
            int t5 = __builtin_nontemporal_load(cs + j + 5);
            int t6 = __builtin_nontemporal_load(cs + j + 6);
            int t7 = __builtin_nontemporal_load(cs + j + 7);
            float f0 = fb[(size_t)t0 * HID + lane];
            float f1 = fb[(size_t)t1 * HID + lane];
            float f2 = fb[(size_t)t2 * HID + lane];
            float f3 = fb[(size_t)t3 * HID + lane];
            float f4 = fb[(size_t)t4 * HID + lane];
            float f5 = fb[(size_t)t5 * HID + lane];
            float f6 = fb[(size_t)t6 * HID + lane];
            float f7 = fb[(size_t)t7 * HID + lane];
            acc += ((f0 + f1) + (f2 + f3)) + ((f4 + f5) + (f6 + f7));
        }
        for (; j < len; ++j)
            acc += fb[(size_t)__builtin_nontemporal_load(cs + j) * HID + lane];
    }
    return acc;
}

// conv1 aggregation + relu + fused W2 GEMM
__launch_bounds__(256)
__global__ void k_agg1(const float* __restrict__ hs, const unsigned short* __restrict__ csr16,
                       const int* __restrict__ rows4, const int* __restrict__ cnt4,
                       const float* __restrict__ dinv, const float* __restrict__ b1,
                       const float* __restrict__ W2, float* __restrict__ hs2) {
    __shared__ float w2[HID * HID];
    __shared__ float h1s[8][HID];
    for (int i = threadIdx.x; i < HID * HID; i += 256) w2[i] = W2[i];
    int lane = threadIdx.x & 31, hw = threadIdx.x >> 5;
    int node = blockIdx.x * 8 + hw;
    float acc = hs[(size_t)node * HID + lane];      // self loop
    acc = agg_chunks(hs, csr16, rows4, cnt4, node, lane, acc);
    float dv = dinv[node];
    h1s[hw][lane] = fmaxf(acc * dv + b1[lane], 0.f);
    __syncthreads();
    float g = 0.f;
#pragma unroll
    for (int k = 0; k < HID; ++k) g += h1s[hw][k] * w2[k * HID + lane];
    hs2[(size_t)node * HID + lane] = g * dv;
}

// conv2 aggregation + relu + fused MLP head
__launch_bounds__(256)
__global__ void k_agg2(const float* __restrict__ hs2, const unsigned short* __restrict__ csr16,
                       const int* __restrict__ rows4, const int* __restrict__ cnt4,
                       const float* __restrict__ dinv, const float* __restrict__ b2,
                       const float* __restrict__ Wl1, const float* __restrict__ bl1,
                       const float* __restrict__ Wl2, const float* __restrict__ bl2,
                       float* __restrict__ out) {
    __shared__ float wl1[HID * HID];
    __shared__ float h2s[8][HID];
    for (int i = threadIdx.x; i < HID * HID; i += 256) wl1[i] = Wl1[i];
    int lane = threadIdx.x & 31, hw = threadIdx.x >> 5;
    int node = blockIdx.x * 8 + hw;
    float acc = hs2[(size_t)node * HID + lane];
    acc = agg_chunks(hs2, csr16, rows4, cnt4, node, lane, acc);
    float h2 = fmaxf(acc * dinv[node] + b2[lane], 0.f);
    h2s[hw][lane] = h2;
    __syncthreads();
    float g = bl1[lane];
#pragma unroll
    for (int k = 0; k < HID; ++k) g += h2s[hw][k] * wl1[k * HID + lane];
    float o = fmaxf(g, 0.f) * Wl2[lane];
#pragma unroll
    for (int off = 16; off; off >>= 1) o += __shfl_down(o, off, 32);
    if (lane == 0) out[node] = o + *bl2;
}

extern "C" void kernel_launch(void* const* d_in, const int* in_sizes, int n_in,
                              void* d_out, int out_size, void* d_ws, size_t ws_size,
                              hipStream_t stream) {
    const float* x   = (const float*)d_in[0];
    const int*   e   = (const int*)d_in[1];
    const float* W1  = (const float*)d_in[2];
    const float* b1  = (const float*)d_in[3];
    const float* W2  = (const float*)d_in[4];
    const float* b2  = (const float*)d_in[5];
    const float* Wl1 = (const float*)d_in[6];
    const float* bl1 = (const float*)d_in[7];
    const float* Wl2 = (const float*)d_in[8];
    const float* bl2 = (const float*)d_in[9];
    float* out = (float*)d_out;

    char* w = (char*)d_ws;
    unsigned int*   ebuf    = (unsigned int*)(w + O_EBUF);
    float*          hs      = (float*)(w + O_HS);
    float*          hs2     = (float*)(w + O_HS2);
    int*            ghist   = (int*)(w + O_GH);
    int*            cursors = (int*)(w + O_CUR);
    unsigned short* csr16   = (unsigned short*)(w + O_CSR);
    int*            rows4   = (int*)(w + O_ROWS4);
    int*            cnt4    = (int*)(w + O_CNT4);
    float*          dinv    = (float*)(w + O_DINV);
    int*            bstart  = (int*)(w + O_BST);
    int*            btot    = (int*)(w + O_BTOT);
    int*            flag    = (int*)(w + O_FLAG);

    const int NB_NODE = N_NODES / 8;          // 12500 exact

    k_detect<<<1, 256, 0, stream>>>((const unsigned int*)e, flag);
    k_hist<<<NBLK, 256, 0, stream>>>(e, flag, ghist);
    k_scan1<<<1, 256, 0, stream>>>(ghist, btot);
    k_scan2<<<1, 1024, 0, stream>>>(btot, bstart);
    k_scan3<<<1, 256, 0, stream>>>(ghist, bstart, cursors);
    k_scatter<<<NBLK, 256, 0, stream>>>(e, flag, cursors, ebuf);
    k_sort2<<<NBKT, 512, 0, stream>>>(ebuf, bstart, csr16, rows4, cnt4, dinv);

    k_gemm1<<<NB_NODE, 256, 0, stream>>>(x, W1, dinv, hs);
    k_agg1<<<NB_NODE, 256, 0, stream>>>(hs, csr16, rows4, cnt4, dinv, b1, W2, hs2);
    k_agg2<<<NB_NODE, 256, 0, stream>>>(hs2, csr16, rows4, cnt4, dinv, b2,
                                        Wl1, bl1, Wl2, bl2, out);
}

// Round 7
// 552.092 us; speedup vs baseline: 1.6575x; 1.6575x over previous
//
#include <hip/hip_runtime.h>

#define N_NODES 100000
#define N_EDGES 6400000
#define IN_CH   128
#define HID     32

#define BKT_SHIFT 9
#define BKT_MASK  511
#define BKT_SZ    512
#define NBKT      196           // ceil(100000/512)
#define NBLK      1024          // histogram/scatter tiles
#define TILE      6250          // 6.4M / 1024 exactly
#define NCHUNK    4
#define CBASE     25000         // nodes per source chunk (3.2 MB of features)

// ---------- ws layout (bytes) ----------
// region A [0, 25.6M): ebuf during build; then hs | hs2 after k_sort2
#define O_EBUF 0u
#define O_HS   0u
#define O_HS2  12800000u
// region B: ghist+cursors during build; csr16 (12.8MB) overlays after scatter
#define O_GH   25600000u        // 1024*196*4 = 802,816
#define O_CUR  26402816u        // 802,816 (dead after k_scatter)
#define O_CSR  25600000u        // ushort[6.4M] = 12,800,000 -> ends 38.4M
// small persistent region
#define O_ROWS4 38400000u       // int[100000][4] = 1,600,000 (node-major, int4/node)
#define O_CNT4  40000000u       // int[100000][4] = 1,600,000
#define O_DINV  41600000u       // 400,000
#define O_BST   42000000u       // (NBKT+1)*4
#define O_BTOT  42002048u       // NBKT*4
#define O_FLAG  42004096u       // 4

// Detect whether edge_index buffer is int64 (high words all zero) or int32.
__global__ void k_detect(const unsigned int* e, int* flag) {
    __shared__ int any;
    if (threadIdx.x == 0) any = 0;
    __syncthreads();
    int acc = 0;
    for (int i = threadIdx.x; i < 4096; i += 256)
        acc |= (e[2 * i + 1] != 0u);
    if (acc) atomicOr(&any, 1);
    __syncthreads();
    if (threadIdx.x == 0) *flag = any ? 0 : 1;   // 1 => int64
}

// Non-temporal streaming edge load (wave-coalesced, read-once). LOADS ONLY.
__device__ __forceinline__ int eload_nt(const int* e, int is64, long long idx) {
    return is64 ? (int)__builtin_nontemporal_load((const long long*)e + idx)
                : __builtin_nontemporal_load(e + (size_t)idx);
}

// Per-tile histogram over destination buckets (LDS int atomics only).
__global__ void k_hist(const int* e, const int* flag, int* ghist) {
    __shared__ int h[NBKT];
    for (int i = threadIdx.x; i < NBKT; i += 256) h[i] = 0;
    __syncthreads();
    int is64 = *flag;
    long long base = (long long)blockIdx.x * TILE;
    for (int k = threadIdx.x; k < TILE; k += 256) {
        int dst = eload_nt(e, is64, (long long)N_EDGES + base + k);
        atomicAdd(&h[dst >> BKT_SHIFT], 1);
    }
    __syncthreads();
    int* g = ghist + blockIdx.x * NBKT;
    for (int i = threadIdx.x; i < NBKT; i += 256) g[i] = h[i];
}

__global__ void k_scan1(const int* __restrict__ ghist, int* __restrict__ btot) {
    int j = blockIdx.x * 256 + threadIdx.x;
    if (j >= NBKT) return;
    int t = 0;
    for (int blk = 0; blk < NBLK; ++blk) t += ghist[blk * NBKT + j];
    btot[j] = t;
}

__global__ void k_scan2(const int* __restrict__ btot, int* __restrict__ bstart) {
    __shared__ int s[1024];
    int t = threadIdx.x;
    int v = (t < NBKT) ? btot[t] : 0;
    s[t] = v;
    __syncthreads();
    for (int off = 1; off < 1024; off <<= 1) {
        int u = (t >= off) ? s[t - off] : 0;
        __syncthreads();
        s[t] += u;
        __syncthreads();
    }
    if (t < NBKT) bstart[t] = s[t] - v;
    if (t == 0) bstart[NBKT] = N_EDGES;
}

__global__ void k_scan3(const int* __restrict__ ghist, const int* __restrict__ bstart,
                        int* __restrict__ cursors) {
    int j = blockIdx.x * 256 + threadIdx.x;
    if (j >= NBKT) return;
    int run = bstart[j];
    for (int blk = 0; blk < NBLK; ++blk) {
        cursors[blk * NBKT + j] = run;
        run += ghist[blk * NBKT + j];
    }
}

// Scatter: local counting sort in LDS, then burst copy-out.
// Each (blk,bin) run is written as a contiguous coalesced burst -> lines fill
// immediately, no partial-line thrash (R3/R5 had 5-6x write amplification).
__launch_bounds__(512)
__global__ void k_scatter(const int* e, const int* flag,
                          const int* __restrict__ ghist, const int* __restrict__ cursors,
                          unsigned int* __restrict__ ebuf) {
    __shared__ unsigned obuf[TILE];          // 25,000 B
    __shared__ unsigned char bid[TILE];      //  6,250 B
    __shared__ int lcur[NBKT];
    __shared__ int gbase[NBKT];
    __shared__ int wsum[8];
    int t = threadIdx.x;
    int blk = blockIdx.x;
    // local exclusive scan of this block's hist row -> lcur (LDS), gbase
    {
        int v = (t < NBKT) ? ghist[blk * NBKT + t] : 0;
        int lane = t & 63, w = t >> 6;
        int p = v;
#pragma unroll
        for (int off = 1; off < 64; off <<= 1) {
            int u = __shfl_up(p, off, 64);
            if (lane >= off) p += u;
        }
        if (lane == 63) wsum[w] = p;
        __syncthreads();
        int woff = 0;
        for (int k = 0; k < w; ++k) woff += wsum[k];
        int excl = woff + p - v;
        if (t < NBKT) {
            lcur[t]  = excl;
            gbase[t] = cursors[blk * NBKT + t] - excl;
        }
    }
    __syncthreads();
    int is64 = *flag;
    long long base = (long long)blk * TILE;
    for (int k = t; k < TILE; k += 512) {
        int src = eload_nt(e, is64, base + k);
        int dst = eload_nt(e, is64, (long long)N_EDGES + base + k);
        int b = dst >> BKT_SHIFT;
        int pos = atomicAdd(&lcur[b], 1);
        obuf[pos] = ((unsigned)src << BKT_SHIFT) | (unsigned)(dst & BKT_MASK);
        bid[pos] = (unsigned char)b;
    }
    __syncthreads();
    for (int i = t; i < TILE; i += 512) {
        int b = bid[i];
        ebuf[gbase[b] + i] = obuf[i];        // consecutive i -> consecutive addr
    }
}

// Per-bucket counting sort by (src_chunk, dst_local): 2048 bins.
// Emits csr16 (chunk-local src ids), node-major rows4/cnt4, dinv. Plain stores.
__launch_bounds__(512)
__global__ void k_sort2(const unsigned int* __restrict__ ebuf, const int* __restrict__ bstart,
                        unsigned short* __restrict__ csr16, int* __restrict__ rows4,
                        int* __restrict__ cnt4, float* __restrict__ dinv) {
    __shared__ int hist[NCHUNK * BKT_SZ];   // 8 KB
    __shared__ int cur[NCHUNK * BKT_SZ];    // 8 KB
    __shared__ int wsum[8];
    int b = blockIdx.x;
    int s0 = bstart[b], e0 = bstart[b + 1];
    int t = threadIdx.x;
#pragma unroll
    for (int i = 0; i < NCHUNK; ++i) hist[i * 512 + t] = 0;
    __syncthreads();
    for (int i = s0 + t; i < e0; i += 512) {
        unsigned v = __builtin_nontemporal_load(&ebuf[i]);
        int src = (int)(v >> BKT_SHIFT);
        int c = src / CBASE;
        atomicAdd(&hist[c * 512 + (v & BKT_MASK)], 1);
    }
    __syncthreads();
    // block-wide exclusive scan over 2048 bins; thread t owns bins 4t..4t+3
    int c0 = hist[4 * t + 0], c1 = hist[4 * t + 1], c2 = hist[4 * t + 2], c3 = hist[4 * t + 3];
    int ssum = c0 + c1 + c2 + c3;
    {
        int lane = t & 63, w = t >> 6;
        int p = ssum;
#pragma unroll
        for (int off = 1; off < 64; off <<= 1) {
            int u = __shfl_up(p, off, 64);
            if (lane >= off) p += u;
        }
        if (lane == 63) wsum[w] = p;
        __syncthreads();
        int woff = 0;
        for (int k = 0; k < w; ++k) woff += wsum[k];
        int excl = woff + p - ssum;
        int e0b = s0 + excl;
        int e1b = e0b + c0, e2b = e1b + c1, e3b = e2b + c2;
        cur[4 * t + 0] = e0b; cur[4 * t + 1] = e1b;
        cur[4 * t + 2] = e2b; cur[4 * t + 3] = e3b;
        int starts[4] = {e0b, e1b, e2b, e3b};
        int cnts[4]   = {c0, c1, c2, c3};
#pragma unroll
        for (int i = 0; i < 4; ++i) {
            int bin = 4 * t + i;
            int c = bin >> 9, dl = bin & BKT_MASK;
            int node = b * BKT_SZ + dl;
            if (node < N_NODES) {
                rows4[node * 4 + c] = starts[i];     // node-major for int4 load
                cnt4[node * 4 + c]  = cnts[i];
            }
        }
    }
    __syncthreads();
    {
        int node = b * BKT_SZ + t;
        if (node < N_NODES) {
            int deg = hist[t] + hist[512 + t] + hist[1024 + t] + hist[1536 + t];
            dinv[node] = rsqrtf((float)(deg + 1));
        }
    }
    for (int i = s0 + t; i < e0; i += 512) {
        unsigned v = __builtin_nontemporal_load(&ebuf[i]);
        int src = (int)(v >> BKT_SHIFT);
        int c = src / CBASE;
        int pos = atomicAdd(&cur[c * 512 + (v & BKT_MASK)], 1);
        csr16[pos] = (unsigned short)(src - c * CBASE);
    }
}

// hs[i][c] = dinv[i] * sum_k x[i][k] * W1[k][c]
__launch_bounds__(256)
__global__ void k_gemm1(const float* __restrict__ x, const float* __restrict__ W1,
                        const float* __restrict__ dinv, float* __restrict__ hs) {
    __shared__ float w[IN_CH * HID];
    __shared__ float xs[8 * IN_CH];
    for (int i = threadIdx.x; i < IN_CH * HID; i += 256) w[i] = W1[i];
    const float4* xb = (const float4*)(x + (size_t)blockIdx.x * 8 * IN_CH);
    ((float4*)xs)[threadIdx.x] = xb[threadIdx.x];
    __syncthreads();
    int lane = threadIdx.x & 31, hw = threadIdx.x >> 5;
    int node = blockIdx.x * 8 + hw;
    const float* xr = xs + hw * IN_CH;
    float acc = 0.f;
#pragma unroll
    for (int k = 0; k < IN_CH; ++k) acc += xr[k] * w[k * HID + lane];
    hs[(size_t)node * HID + lane] = acc * dinv[node];
}

// Register-resident 4-chunk gather loop (shared by both aggs). Plain loads:
// csr16 lines are broadcast-read 32 lanes at a time and reused within L1.
__device__ __forceinline__ float agg_chunks(const float* __restrict__ feat,
                                            const unsigned short* __restrict__ csr16,
                                            const int* __restrict__ rows4,
                                            const int* __restrict__ cnt4,
                                            int node, int lane, float acc) {
    int4 rs = ((const int4*)rows4)[node];
    int4 cn = ((const int4*)cnt4)[node];
    int starts[4] = {rs.x, rs.y, rs.z, rs.w};
    int lens[4]   = {cn.x, cn.y, cn.z, cn.w};
#pragma unroll
    for (int c = 0; c < NCHUNK; ++c) {
        const unsigned short* cs = csr16 + starts[c];
        const float* fb = feat + (size_t)(c * CBASE) * HID;
        int len = lens[c];
        int j = 0;
        for (; j + 8 <= len; j += 8) {
            int t0 = cs[j + 0], t1 = cs[j + 1], t2 = cs[j + 2], t3 = cs[j + 3];
            int t4 = cs[j + 4], t5 = cs[j + 5], t6 = cs[j + 6], t7 = cs[j + 7];
            float f0 = fb[t0 * HID + lane];
            float f1 = fb[t1 * HID + lane];
            float f2 = fb[t2 * HID + lane];
            float f3 = fb[t3 * HID + lane];
            float f4 = fb[t4 * HID + lane];
            float f5 = fb[t5 * HID + lane];
            float f6 = fb[t6 * HID + lane];
            float f7 = fb[t7 * HID + lane];
            acc += ((f0 + f1) + (f2 + f3)) + ((f4 + f5) + (f6 + f7));
        }
        for (; j < len; ++j) acc += fb[(int)cs[j] * HID + lane];
    }
    return acc;
}

// conv1 aggregation + relu + fused W2 GEMM
__launch_bounds__(256)
__global__ void k_agg1(const float* __restrict__ hs, const unsigned short* __restrict__ csr16,
                       const int* __restrict__ rows4, const int* __restrict__ cnt4,
                       const float* __restrict__ dinv, const float* __restrict__ b1,
                       const float* __restrict__ W2, float* __restrict__ hs2) {
    __shared__ float w2[HID * HID];
    __shared__ float h1s[8][HID];
    for (int i = threadIdx.x; i < HID * HID; i += 256) w2[i] = W2[i];
    int lane = threadIdx.x & 31, hw = threadIdx.x >> 5;
    int node = blockIdx.x * 8 + hw;
    float acc = hs[(size_t)node * HID + lane];      // self loop
    acc = agg_chunks(hs, csr16, rows4, cnt4, node, lane, acc);
    float dv = dinv[node];
    h1s[hw][lane] = fmaxf(acc * dv + b1[lane], 0.f);
    __syncthreads();
    float g = 0.f;
#pragma unroll
    for (int k = 0; k < HID; ++k) g += h1s[hw][k] * w2[k * HID + lane];
    hs2[(size_t)node * HID + lane] = g * dv;
}

// conv2 aggregation + relu + fused MLP head
__launch_bounds__(256)
__global__ void k_agg2(const float* __restrict__ hs2, const unsigned short* __restrict__ csr16,
                       const int* __restrict__ rows4, const int* __restrict__ cnt4,
                       const float* __restrict__ dinv, const float* __restrict__ b2,
                       const float* __restrict__ Wl1, const float* __restrict__ bl1,
                       const float* __restrict__ Wl2, const float* __restrict__ bl2,
                       float* __restrict__ out) {
    __shared__ float wl1[HID * HID];
    __shared__ float h2s[8][HID];
    for (int i = threadIdx.x; i < HID * HID; i += 256) wl1[i] = Wl1[i];
    int lane = threadIdx.x & 31, hw = threadIdx.x >> 5;
    int node = blockIdx.x * 8 + hw;
    float acc = hs2[(size_t)node * HID + lane];
    acc = agg_chunks(hs2, csr16, rows4, cnt4, node, lane, acc);
    float h2 = fmaxf(acc * dinv[node] + b2[lane], 0.f);
    h2s[hw][lane] = h2;
    __syncthreads();
    float g = bl1[lane];
#pragma unroll
    for (int k = 0; k < HID; ++k) g += h2s[hw][k] * wl1[k * HID + lane];
    float o = fmaxf(g, 0.f) * Wl2[lane];
#pragma unroll
    for (int off = 16; off; off >>= 1) o += __shfl_down(o, off, 32);
    if (lane == 0) out[node] = o + *bl2;
}

extern "C" void kernel_launch(void* const* d_in, const int* in_sizes, int n_in,
                              void* d_out, int out_size, void* d_ws, size_t ws_size,
                              hipStream_t stream) {
    const float* x   = (const float*)d_in[0];
    const int*   e   = (const int*)d_in[1];
    const float* W1  = (const float*)d_in[2];
    const float* b1  = (const float*)d_in[3];
    const float* W2  = (const float*)d_in[4];
    const float* b2  = (const float*)d_in[5];
    const float* Wl1 = (const float*)d_in[6];
    const float* bl1 = (const float*)d_in[7];
    const float* Wl2 = (const float*)d_in[8];
    const float* bl2 = (const float*)d_in[9];
    float* out = (float*)d_out;

    char* w = (char*)d_ws;
    unsigned int*   ebuf    = (unsigned int*)(w + O_EBUF);
    float*          hs      = (float*)(w + O_HS);
    float*          hs2     = (float*)(w + O_HS2);
    int*            ghist   = (int*)(w + O_GH);
    int*            cursors = (int*)(w + O_CUR);
    unsigned short* csr16   = (unsigned short*)(w + O_CSR);
    int*            rows4   = (int*)(w + O_ROWS4);
    int*            cnt4    = (int*)(w + O_CNT4);
    float*          dinv    = (float*)(w + O_DINV);
    int*            bstart  = (int*)(w + O_BST);
    int*            btot    = (int*)(w + O_BTOT);
    int*            flag    = (int*)(w + O_FLAG);

    const int NB_NODE = N_NODES / 8;          // 12500 exact

    k_detect<<<1, 256, 0, stream>>>((const unsigned int*)e, flag);
    k_hist<<<NBLK, 256, 0, stream>>>(e, flag, ghist);
    k_scan1<<<1, 256, 0, stream>>>(ghist, btot);
    k_scan2<<<1, 1024, 0, stream>>>(btot, bstart);
    k_scan3<<<1, 256, 0, stream>>>(ghist, bstart, cursors);
    k_scatter<<<NBLK, 512, 0, stream>>>(e, flag, ghist, cursors, ebuf);
    k_sort2<<<NBKT, 512, 0, stream>>>(ebuf, bstart, csr16, rows4, cnt4, dinv);

    k_gemm1<<<NB_NODE, 256, 0, stream>>>(x, W1, dinv, hs);
    k_agg1<<<NB_NODE, 256, 0, stream>>>(hs, csr16, rows4, cnt4, dinv, b1, W2, hs2);
    k_agg2<<<NB_NODE, 256, 0, stream>>>(hs2, csr16, rows4, cnt4, dinv, b2,
                                        Wl1, bl1, Wl2, bl2, out);
}

// Round 8
// 473.031 us; speedup vs baseline: 1.9346x; 1.1671x over previous
//
#include <hip/hip_runtime.h>

#define N_NODES 100000
#define N_EDGES 6400000
#define IN_CH   128
#define HID     32

#define BKT_SHIFT 9
#define BKT_MASK  511
#define BKT_SZ    512
#define NBKT      196           // ceil(100000/512)
#define NBLK      1024          // histogram/scatter tiles
#define TILE      6250          // 6.4M / 1024 exactly

// ---------- ws layout (bytes) ----------
// [0, 25.6M): ebuf during build; then hs | hs2 after sort2b
#define O_EBUF 0u
#define O_HS   0u
#define O_HS2  12800000u
// ghist (hist->scatter) then ghist2 (sort2a->sort2b) overlay: both 802,816 B
#define O_GH   25600000u
// cursors (scan3->scatter) then csr32 (sort2b->aggs) overlay at 26,402,816
#define O_CUR  26402816u
#define O_CSR  26402816u        // int[6.4M] = 25,600,000 -> ends 52,002,816
#define O_ROWS 52002816u        // (N_NODES+1)*4 = 400,004
#define O_BST  52402824u        // (NBKT+1)*4
#define O_BTOT 52403616u        // NBKT*4
#define O_FLAG 52404400u        // 4
// total ~52.41 MB (< 52.80 MB proven in R1)

// Detect whether edge_index buffer is int64 (high words all zero) or int32.
__global__ void k_detect(const unsigned int* e, int* flag) {
    __shared__ int any;
    if (threadIdx.x == 0) any = 0;
    __syncthreads();
    int acc = 0;
    for (int i = threadIdx.x; i < 4096; i += 256)
        acc |= (e[2 * i + 1] != 0u);
    if (acc) atomicOr(&any, 1);
    __syncthreads();
    if (threadIdx.x == 0) *flag = any ? 0 : 1;   // 1 => int64
}

// Non-temporal streaming edge load (wave-coalesced, read-once). LOADS ONLY.
__device__ __forceinline__ int eload_nt(const int* e, int is64, long long idx) {
    return is64 ? (int)__builtin_nontemporal_load((const long long*)e + idx)
                : __builtin_nontemporal_load(e + (size_t)idx);
}

// Per-tile histogram over destination buckets (LDS int atomics only).
__global__ void k_hist(const int* e, const int* flag, int* ghist) {
    __shared__ int h[NBKT];
    for (int i = threadIdx.x; i < NBKT; i += 256) h[i] = 0;
    __syncthreads();
    int is64 = *flag;
    long long base = (long long)blockIdx.x * TILE;
    for (int k = threadIdx.x; k < TILE; k += 256) {
        int dst = eload_nt(e, is64, (long long)N_EDGES + base + k);
        atomicAdd(&h[dst >> BKT_SHIFT], 1);
    }
    __syncthreads();
    int* g = ghist + blockIdx.x * NBKT;
    for (int i = threadIdx.x; i < NBKT; i += 256) g[i] = h[i];
}

__global__ void k_scan1(const int* __restrict__ ghist, int* __restrict__ btot) {
    int j = blockIdx.x * 256 + threadIdx.x;
    if (j >= NBKT) return;
    int t = 0;
    for (int blk = 0; blk < NBLK; ++blk) t += ghist[blk * NBKT + j];
    btot[j] = t;
}

__global__ void k_scan2(const int* __restrict__ btot, int* __restrict__ bstart) {
    __shared__ int s[1024];
    int t = threadIdx.x;
    int v = (t < NBKT) ? btot[t] : 0;
    s[t] = v;
    __syncthreads();
    for (int off = 1; off < 1024; off <<= 1) {
        int u = (t >= off) ? s[t - off] : 0;
        __syncthreads();
        s[t] += u;
        __syncthreads();
    }
    if (t < NBKT) bstart[t] = s[t] - v;
    if (t == 0) bstart[NBKT] = N_EDGES;
}

__global__ void k_scan3(const int* __restrict__ ghist, const int* __restrict__ bstart,
                        int* __restrict__ cursors) {
    int j = blockIdx.x * 256 + threadIdx.x;
    if (j >= NBKT) return;
    int run = bstart[j];
    for (int blk = 0; blk < NBLK; ++blk) {
        cursors[blk * NBKT + j] = run;
        run += ghist[blk * NBKT + j];
    }
}

// Scatter: local counting sort in LDS, then burst copy-out (full-line runs).
__launch_bounds__(512)
__global__ void k_scatter(const int* e, const int* flag,
                          const int* __restrict__ ghist, const int* __restrict__ cursors,
                          unsigned int* __restrict__ ebuf) {
    __shared__ unsigned obuf[TILE];          // 25,000 B
    __shared__ unsigned char bid[TILE];      //  6,250 B
    __shared__ int lcur[NBKT];
    __shared__ int gbase[NBKT];
    __shared__ int wsum[8];
    int t = threadIdx.x;
    int blk = blockIdx.x;
    {
        int v = (t < NBKT) ? ghist[blk * NBKT + t] : 0;
        int lane = t & 63, w = t >> 6;
        int p = v;
#pragma unroll
        for (int off = 1; off < 64; off <<= 1) {
            int u = __shfl_up(p, off, 64);
            if (lane >= off) p += u;
        }
        if (lane == 63) wsum[w] = p;
        __syncthreads();
        int woff = 0;
        for (int k = 0; k < w; ++k) woff += wsum[k];
        int excl = woff + p - v;
        if (t < NBKT) {
            lcur[t]  = excl;
            gbase[t] = cursors[blk * NBKT + t] - excl;
        }
    }
    __syncthreads();
    int is64 = *flag;
    long long base = (long long)blk * TILE;
    for (int k = t; k < TILE; k += 512) {
        int src = eload_nt(e, is64, base + k);
        int dst = eload_nt(e, is64, (long long)N_EDGES + base + k);
        int b = dst >> BKT_SHIFT;
        int pos = atomicAdd(&lcur[b], 1);
        obuf[pos] = ((unsigned)src << BKT_SHIFT) | (unsigned)(dst & BKT_MASK);
        bid[pos] = (unsigned char)b;
    }
    __syncthreads();
    for (int i = t; i < TILE; i += 512) {
        int b = bid[i];
        ebuf[gbase[b] + i] = obuf[i];        // consecutive i -> consecutive addr
    }
}

// sort2a: per (bucket, half) histogram of dst-local bins -> ghist2.
__launch_bounds__(512)
__global__ void k_sort2a(const unsigned int* __restrict__ ebuf, const int* __restrict__ bstart,
                         int* __restrict__ ghist2) {
    __shared__ int hist[BKT_SZ];
    int b = blockIdx.x >> 1, h = blockIdx.x & 1;
    int s0 = bstart[b], e0 = bstart[b + 1];
    int mid = (s0 + e0) >> 1;
    int lo = h ? mid : s0, hi = h ? e0 : mid;
    hist[threadIdx.x] = 0;
    __syncthreads();
    for (int i = lo + (int)threadIdx.x; i < hi; i += 512)
        atomicAdd(&hist[__builtin_nontemporal_load(&ebuf[i]) & BKT_MASK], 1);
    __syncthreads();
    ghist2[(b * 2 + h) * BKT_SZ + threadIdx.x] = hist[threadIdx.x];
}

// sort2b: per (bucket, half) scan + scatter into node-sorted csr32; h==0 writes rows.
__launch_bounds__(512)
__global__ void k_sort2b(const unsigned int* __restrict__ ebuf, const int* __restrict__ bstart,
                         const int* __restrict__ ghist2, int* __restrict__ csr,
                         int* __restrict__ rows) {
    __shared__ int cur[BKT_SZ];
    __shared__ int wsum[8];
    int b = blockIdx.x >> 1, h = blockIdx.x & 1;
    int s0 = bstart[b], e0 = bstart[b + 1];
    int mid = (s0 + e0) >> 1;
    int lo = h ? mid : s0, hi = h ? e0 : mid;
    int t = threadIdx.x;                    // t == bin id
    int c0 = ghist2[(b * 2 + 0) * BKT_SZ + t];
    int c1 = ghist2[(b * 2 + 1) * BKT_SZ + t];
    int tot = c0 + c1;
    int lane = t & 63, w = t >> 6;
    int p = tot;
#pragma unroll
    for (int off = 1; off < 64; off <<= 1) {
        int u = __shfl_up(p, off, 64);
        if (lane >= off) p += u;
    }
    if (lane == 63) wsum[w] = p;
    __syncthreads();
    int woff = 0;
    for (int k = 0; k < w; ++k) woff += wsum[k];
    int binstart = s0 + woff + p - tot;     // exclusive within bucket
    cur[t] = binstart + (h ? c0 : 0);
    int node = b * BKT_SZ + t;
    if (h == 0 && node <= N_NODES) rows[node] = binstart;  // node==N -> N_EDGES
    __syncthreads();
    for (int i = lo + t; i < hi; i += 512) {
        unsigned v = __builtin_nontemporal_load(&ebuf[i]);
        int pos = atomicAdd(&cur[v & BKT_MASK], 1);
        csr[pos] = (int)(v >> BKT_SHIFT);
    }
}

// hs[i][c] = dinv[i] * sum_k x[i][k] * W1[k][c]
__launch_bounds__(256)
__global__ void k_gemm1(const float* __restrict__ x, const float* __restrict__ W1,
                        const int* __restrict__ rows, float* __restrict__ hs) {
    __shared__ float w[IN_CH * HID];
    __shared__ float xs[8 * IN_CH];
    for (int i = threadIdx.x; i < IN_CH * HID; i += 256) w[i] = W1[i];
    const float4* xb = (const float4*)(x + (size_t)blockIdx.x * 8 * IN_CH);
    ((float4*)xs)[threadIdx.x] = xb[threadIdx.x];
    __syncthreads();
    int lane = threadIdx.x & 31, hw = threadIdx.x >> 5;
    int node = blockIdx.x * 8 + hw;
    float dv = rsqrtf((float)(rows[node + 1] - rows[node] + 1));
    const float* xr = xs + hw * IN_CH;
    float acc = 0.f;
#pragma unroll
    for (int k = 0; k < IN_CH; ++k) acc += xr[k] * w[k * HID + lane];
    hs[(size_t)node * HID + lane] = acc * dv;
}

// ILP-16 gather loop: 16 independent row-loads in flight per half-wave.
__device__ __forceinline__ float gather_row(const float* __restrict__ feat,
                                            const int* __restrict__ cs,
                                            int len, int lane, float acc) {
    int j = 0;
    for (; j + 16 <= len; j += 16) {
        int idx[16];
#pragma unroll
        for (int u = 0; u < 16; ++u) idx[u] = cs[j + u];
        float f[16];
#pragma unroll
        for (int u = 0; u < 16; ++u) f[u] = feat[(size_t)idx[u] * HID + lane];
        acc += (((f[0] + f[1]) + (f[2] + f[3])) + ((f[4] + f[5]) + (f[6] + f[7])))
             + (((f[8] + f[9]) + (f[10] + f[11])) + ((f[12] + f[13]) + (f[14] + f[15])));
    }
    for (; j + 8 <= len; j += 8) {
        int idx[8];
#pragma unroll
        for (int u = 0; u < 8; ++u) idx[u] = cs[j + u];
        float f[8];
#pragma unroll
        for (int u = 0; u < 8; ++u) f[u] = feat[(size_t)idx[u] * HID + lane];
        acc += ((f[0] + f[1]) + (f[2] + f[3])) + ((f[4] + f[5]) + (f[6] + f[7]));
    }
    for (; j < len; ++j) acc += feat[(size_t)cs[j] * HID + lane];
    return acc;
}

// conv1 aggregation + relu + fused W2 GEMM
__launch_bounds__(256)
__global__ void k_agg1(const float* __restrict__ hs, const int* __restrict__ csr,
                       const int* __restrict__ rows, const float* __restrict__ b1,
                       const float* __restrict__ W2, float* __restrict__ hs2) {
    __shared__ float w2[HID * HID];
    __shared__ float h1s[8][HID];
    for (int i = threadIdx.x; i < HID * HID; i += 256) w2[i] = W2[i];
    int lane = threadIdx.x & 31, hw = threadIdx.x >> 5;
    int node = blockIdx.x * 8 + hw;
    int r0 = rows[node], r1 = rows[node + 1];
    float dv = rsqrtf((float)(r1 - r0 + 1));
    float acc = hs[(size_t)node * HID + lane];      // self loop
    acc = gather_row(hs, csr + r0, r1 - r0, lane, acc);
    h1s[hw][lane] = fmaxf(acc * dv + b1[lane], 0.f);
    __syncthreads();
    float g = 0.f;
#pragma unroll
    for (int k = 0; k < HID; ++k) g += h1s[hw][k] * w2[k * HID + lane];
    hs2[(size_t)node * HID + lane] = g * dv;
}

// conv2 aggregation + relu + fused MLP head
__launch_bounds__(256)
__global__ void k_agg2(const float* __restrict__ hs2, const int* __restrict__ csr,
                       const int* __restrict__ rows, const float* __restrict__ b2,
                       const float* __restrict__ Wl1, const float* __restrict__ bl1,
                       const float* __restrict__ Wl2, const float* __restrict__ bl2,
                       float* __restrict__ out) {
    __shared__ float wl1[HID * HID];
    __shared__ float h2s[8][HID];
    for (int i = threadIdx.x; i < HID * HID; i += 256) wl1[i] = Wl1[i];
    int lane = threadIdx.x & 31, hw = threadIdx.x >> 5;
    int node = blockIdx.x * 8 + hw;
    int r0 = rows[node], r1 = rows[node + 1];
    float dv = rsqrtf((float)(r1 - r0 + 1));
    float acc = hs2[(size_t)node * HID + lane];
    acc = gather_row(hs2, csr + r0, r1 - r0, lane, acc);
    float h2 = fmaxf(acc * dv + b2[lane], 0.f);
    h2s[hw][lane] = h2;
    __syncthreads();
    float g = bl1[lane];
#pragma unroll
    for (int k = 0; k < HID; ++k) g += h2s[hw][k] * wl1[k * HID + lane];
    float o = fmaxf(g, 0.f) * Wl2[lane];
#pragma unroll
    for (int off = 16; off; off >>= 1) o += __shfl_down(o, off, 32);
    if (lane == 0) out[node] = o + *bl2;
}

extern "C" void kernel_launch(void* const* d_in, const int* in_sizes, int n_in,
                              void* d_out, int out_size, void* d_ws, size_t ws_size,
                              hipStream_t stream) {
    const float* x   = (const float*)d_in[0];
    const int*   e   = (const int*)d_in[1];
    const float* W1  = (const float*)d_in[2];
    const float* b1  = (const float*)d_in[3];
    const float* W2  = (const float*)d_in[4];
    const float* b2  = (const float*)d_in[5];
    const float* Wl1 = (const float*)d_in[6];
    const float* bl1 = (const float*)d_in[7];
    const float* Wl2 = (const float*)d_in[8];
    const float* bl2 = (const float*)d_in[9];
    float* out = (float*)d_out;

    char* w = (char*)d_ws;
    unsigned int* ebuf    = (unsigned int*)(w + O_EBUF);
    float*        hs      = (float*)(w + O_HS);
    float*        hs2     = (float*)(w + O_HS2);
    int*          ghist   = (int*)(w + O_GH);     // also ghist2 (overlay)
    int*          cursors = (int*)(w + O_CUR);
    int*          csr     = (int*)(w + O_CSR);    // overlays cursors (dead)
    int*          rows    = (int*)(w + O_ROWS);
    int*          bstart  = (int*)(w + O_BST);
    int*          btot    = (int*)(w + O_BTOT);
    int*          flag    = (int*)(w + O_FLAG);

    const int NB_NODE = N_NODES / 8;          // 12500 exact

    k_detect<<<1, 256, 0, stream>>>((const unsigned int*)e, flag);
    k_hist<<<NBLK, 256, 0, stream>>>(e, flag, ghist);
    k_scan1<<<1, 256, 0, stream>>>(ghist, btot);
    k_scan2<<<1, 1024, 0, stream>>>(btot, bstart);
    k_scan3<<<1, 256, 0, stream>>>(ghist, bstart, cursors);
    k_scatter<<<NBLK, 512, 0, stream>>>(e, flag, ghist, cursors, ebuf);
    k_sort2a<<<NBKT * 2, 512, 0, stream>>>(ebuf, bstart, ghist);
    k_sort2b<<<NBKT * 2, 512, 0, stream>>>(ebuf, bstart, ghist, csr, rows);

    k_gemm1<<<NB_NODE, 256, 0, stream>>>(x, W1, rows, hs);
    k_agg1<<<NB_NODE, 256, 0, stream>>>(hs, csr, rows, b1, W2, hs2);
    k_agg2<<<NB_NODE, 256, 0, stream>>>(hs2, csr, rows, b2,
                                        Wl1, bl1, Wl2, bl2, out);
}

// Round 9
// 373.831 us; speedup vs baseline: 2.4479x; 1.2654x over previous
//
#include <hip/hip_runtime.h>

#define N_NODES 100000
#define N_EDGES 6400000
#define IN_CH   128
#define HID     32

#define BKT_SHIFT 9
#define BKT_MASK  511
#define BKT_SZ    512
#define NBKT      196           // ceil(100000/512)
#define NBLK      1024          // histogram/scatter tiles
#define TILE      6250          // 6.4M / 1024 exactly
#define QMAX      8704          // quarter-bucket LDS staging capacity (max ~8330 expected)

// ---------- ws layout (bytes) ----------
// [0, 25.6M): ebuf during build; then hs | hs2 after sort2b
#define O_EBUF 0u
#define O_HS   0u
#define O_HS2  12800000u
// ghist int[1024*196]=802,816 (hist->scatter); then ghist2 ushort[196*4*512]=802,816 (sort2a->sort2b)
#define O_GH   25600000u
// cursors (scan3->scatter) then csr32 (sort2b->aggs) overlay at 26,402,816
#define O_CUR  26402816u
#define O_CSR  26402816u        // int[6.4M] = 25,600,000 -> ends 52,002,816
#define O_ROWS 52002816u        // (N_NODES+1)*4 = 400,004
#define O_BST  52402824u        // (NBKT+1)*4
#define O_BTOT 52403616u        // NBKT*4
#define O_FLAG 52404400u        // 4
// total ~52.40 MB (<= 52.80 MB proven in R1)

// Detect whether edge_index buffer is int64 (high words all zero) or int32.
__global__ void k_detect(const unsigned int* e, int* flag) {
    __shared__ int any;
    if (threadIdx.x == 0) any = 0;
    __syncthreads();
    int acc = 0;
    for (int i = threadIdx.x; i < 4096; i += 256)
        acc |= (e[2 * i + 1] != 0u);
    if (acc) atomicOr(&any, 1);
    __syncthreads();
    if (threadIdx.x == 0) *flag = any ? 0 : 1;   // 1 => int64
}

// Non-temporal streaming edge load (wave-coalesced, read-once). LOADS ONLY.
__device__ __forceinline__ int eload_nt(const int* e, int is64, long long idx) {
    return is64 ? (int)__builtin_nontemporal_load((const long long*)e + idx)
                : __builtin_nontemporal_load(e + (size_t)idx);
}

// Per-tile histogram over destination buckets (LDS int atomics only).
__global__ void k_hist(const int* e, const int* flag, int* ghist) {
    __shared__ int h[NBKT];
    for (int i = threadIdx.x; i < NBKT; i += 256) h[i] = 0;
    __syncthreads();
    int is64 = *flag;
    long long base = (long long)blockIdx.x * TILE;
    for (int k = threadIdx.x; k < TILE; k += 256) {
        int dst = eload_nt(e, is64, (long long)N_EDGES + base + k);
        atomicAdd(&h[dst >> BKT_SHIFT], 1);
    }
    __syncthreads();
    int* g = ghist + blockIdx.x * NBKT;
    for (int i = threadIdx.x; i < NBKT; i += 256) g[i] = h[i];
}

// btot[j] = sum over tiles of ghist[blk][j]; one block per bucket, wave reduce.
__global__ void k_scan1(const int* __restrict__ ghist, int* __restrict__ btot) {
    int j = blockIdx.x;
    int t = threadIdx.x;             // 64 threads
    int s = 0;
    for (int blk = t; blk < NBLK; blk += 64) s += ghist[blk * NBKT + j];
#pragma unroll
    for (int off = 32; off; off >>= 1) s += __shfl_down(s, off, 64);
    if (t == 0) btot[j] = s;
}

__global__ void k_scan2(const int* __restrict__ btot, int* __restrict__ bstart) {
    __shared__ int s[1024];
    int t = threadIdx.x;
    int v = (t < NBKT) ? btot[t] : 0;
    s[t] = v;
    __syncthreads();
    for (int off = 1; off < 1024; off <<= 1) {
        int u = (t >= off) ? s[t - off] : 0;
        __syncthreads();
        s[t] += u;
        __syncthreads();
    }
    if (t < NBKT) bstart[t] = s[t] - v;
    if (t == 0) bstart[NBKT] = N_EDGES;
}

__global__ void k_scan3(const int* __restrict__ ghist, const int* __restrict__ bstart,
                        int* __restrict__ cursors) {
    int j = blockIdx.x * 256 + threadIdx.x;
    if (j >= NBKT) return;
    int run = bstart[j];
    for (int blk = 0; blk < NBLK; ++blk) {
        cursors[blk * NBKT + j] = run;
        run += ghist[blk * NBKT + j];
    }
}

// Scatter: local counting sort in LDS, then burst copy-out (full-line runs).
__launch_bounds__(512)
__global__ void k_scatter(const int* e, const int* flag,
                          const int* __restrict__ ghist, const int* __restrict__ cursors,
                          unsigned int* __restrict__ ebuf) {
    __shared__ unsigned obuf[TILE];          // 25,000 B
    __shared__ unsigned char bid[TILE];      //  6,250 B
    __shared__ int lcur[NBKT];
    __shared__ int gbase[NBKT];
    __shared__ int wsum[8];
    int t = threadIdx.x;
    int blk = blockIdx.x;
    {
        int v = (t < NBKT) ? ghist[blk * NBKT + t] : 0;
        int lane = t & 63, w = t >> 6;
        int p = v;
#pragma unroll
        for (int off = 1; off < 64; off <<= 1) {
            int u = __shfl_up(p, off, 64);
            if (lane >= off) p += u;
        }
        if (lane == 63) wsum[w] = p;
        __syncthreads();
        int woff = 0;
        for (int k = 0; k < w; ++k) woff += wsum[k];
        int excl = woff + p - v;
        if (t < NBKT) {
            lcur[t]  = excl;
            gbase[t] = cursors[blk * NBKT + t] - excl;
        }
    }
    __syncthreads();
    int is64 = *flag;
    long long base = (long long)blk * TILE;
    for (int k = t; k < TILE; k += 512) {
        int src = eload_nt(e, is64, base + k);
        int dst = eload_nt(e, is64, (long long)N_EDGES + base + k);
        int b = dst >> BKT_SHIFT;
        int pos = atomicAdd(&lcur[b], 1);
        obuf[pos] = ((unsigned)src << BKT_SHIFT) | (unsigned)(dst & BKT_MASK);
        bid[pos] = (unsigned char)b;
    }
    __syncthreads();
    for (int i = t; i < TILE; i += 512) {
        int b = bid[i];
        ebuf[gbase[b] + i] = obuf[i];        // consecutive i -> consecutive addr
    }
}

// sort2a: per (bucket, quarter) histogram of dst-local bins -> gh2 (ushort).
__launch_bounds__(512)
__global__ void k_sort2a(const unsigned int* __restrict__ ebuf, const int* __restrict__ bstart,
                         unsigned short* __restrict__ gh2) {
    __shared__ int hist[BKT_SZ];
    int b = blockIdx.x >> 2, q = blockIdx.x & 3;
    int s0 = bstart[b], e0 = bstart[b + 1], len = e0 - s0;
    int lo = s0 + (int)((long long)len * q / 4);
    int hi = s0 + (int)((long long)len * (q + 1) / 4);
    hist[threadIdx.x] = 0;
    __syncthreads();
    for (int i = lo + (int)threadIdx.x; i < hi; i += 512)
        atomicAdd(&hist[__builtin_nontemporal_load(&ebuf[i]) & BKT_MASK], 1);
    __syncthreads();
    gh2[(b * 4 + q) * BKT_SZ + threadIdx.x] = (unsigned short)hist[threadIdx.x];
}

// sort2b: per (bucket, quarter) — scan bucket bins from 4 quarter-hists, then
// LDS counting sort of this quarter + burst copy-out (k_scatter's cure).
__launch_bounds__(512)
__global__ void k_sort2b(const unsigned int* __restrict__ ebuf, const int* __restrict__ bstart,
                         const unsigned short* __restrict__ gh2, int* __restrict__ csr,
                         int* __restrict__ rows) {
    __shared__ unsigned obuf[QMAX];          // 34,816 B
    __shared__ unsigned short bid[QMAX];     // 17,408 B
    __shared__ int lcur[BKT_SZ];             // 2 KB
    __shared__ int gbase[BKT_SZ];            // 2 KB
    __shared__ int wsA[8], wsB[8];
    int b = blockIdx.x >> 2, q = blockIdx.x & 3;
    int s0 = bstart[b], e0 = bstart[b + 1], len = e0 - s0;
    int lo = s0 + (int)((long long)len * q / 4);
    int hi = s0 + (int)((long long)len * (q + 1) / 4);
    int t = threadIdx.x;                     // t == bin id
    int h0 = gh2[(b * 4 + 0) * BKT_SZ + t];
    int h1 = gh2[(b * 4 + 1) * BKT_SZ + t];
    int h2 = gh2[(b * 4 + 2) * BKT_SZ + t];
    int h3 = gh2[(b * 4 + 3) * BKT_SZ + t];
    int tot = h0 + h1 + h2 + h3;
    int hq = (q == 0) ? h0 : (q == 1) ? h1 : (q == 2) ? h2 : h3;
    // fused block-wide exclusive scans: (tot) -> bucket binstart, (hq) -> local offset
    int lane = t & 63, w = t >> 6;
    int p1 = tot, p2 = hq;
#pragma unroll
    for (int off = 1; off < 64; off <<= 1) {
        int u1 = __shfl_up(p1, off, 64);
        int u2 = __shfl_up(p2, off, 64);
        if (lane >= off) { p1 += u1; p2 += u2; }
    }
    if (lane == 63) { wsA[w] = p1; wsB[w] = p2; }
    __syncthreads();
    int woffA = 0, woffB = 0;
    for (int k = 0; k < w; ++k) { woffA += wsA[k]; woffB += wsB[k]; }
    int binstart = s0 + woffA + p1 - tot;    // bucket-wide bin start
    int lexcl    = woffB + p2 - hq;          // this quarter's local packed offset
    int qs = binstart + ((q > 0) ? h0 : 0) + ((q > 1) ? h1 : 0) + ((q > 2) ? h2 : 0);
    lcur[t]  = lexcl;
    gbase[t] = qs - lexcl;
    int node = b * BKT_SZ + t;
    if (q == 0 && node <= N_NODES) rows[node] = binstart;
    __syncthreads();
    for (int i = lo + t; i < hi; i += 512) {
        unsigned v = __builtin_nontemporal_load(&ebuf[i]);
        int bin = v & BKT_MASK;
        int pos = atomicAdd(&lcur[bin], 1);
        obuf[pos] = v >> BKT_SHIFT;
        bid[pos] = (unsigned short)bin;
    }
    __syncthreads();
    int qlen = hi - lo;
    for (int i = t; i < qlen; i += 512) {
        int bn = bid[i];
        csr[gbase[bn] + i] = (int)obuf[i];   // consecutive i -> consecutive addr
    }
}

// hs[i][c] = dinv[i] * sum_k x[i][k] * W1[k][c]
__launch_bounds__(256)
__global__ void k_gemm1(const float* __restrict__ x, const float* __restrict__ W1,
                        const int* __restrict__ rows, float* __restrict__ hs) {
    __shared__ float w[IN_CH * HID];
    __shared__ float xs[8 * IN_CH];
    for (int i = threadIdx.x; i < IN_CH * HID; i += 256) w[i] = W1[i];
    const float4* xb = (const float4*)(x + (size_t)blockIdx.x * 8 * IN_CH);
    ((float4*)xs)[threadIdx.x] = xb[threadIdx.x];
    __syncthreads();
    int lane = threadIdx.x & 31, hw = threadIdx.x >> 5;
    int node = blockIdx.x * 8 + hw;
    float dv = rsqrtf((float)(rows[node + 1] - rows[node] + 1));
    const float* xr = xs + hw * IN_CH;
    float acc = 0.f;
#pragma unroll
    for (int k = 0; k < IN_CH; ++k) acc += xr[k] * w[k * HID + lane];
    hs[(size_t)node * HID + lane] = acc * dv;
}

// ILP-16 gather loop: 16 independent row-loads in flight per half-wave.
__device__ __forceinline__ float gather_row(const float* __restrict__ feat,
                                            const int* __restrict__ cs,
                                            int len, int lane, float acc) {
    int j = 0;
    for (; j + 16 <= len; j += 16) {
        int idx[16];
#pragma unroll
        for (int u = 0; u < 16; ++u) idx[u] = cs[j + u];
        float f[16];
#pragma unroll
        for (int u = 0; u < 16; ++u) f[u] = feat[(size_t)idx[u] * HID + lane];
        acc += (((f[0] + f[1]) + (f[2] + f[3])) + ((f[4] + f[5]) + (f[6] + f[7])))
             + (((f[8] + f[9]) + (f[10] + f[11])) + ((f[12] + f[13]) + (f[14] + f[15])));
    }
    for (; j + 8 <= len; j += 8) {
        int idx[8];
#pragma unroll
        for (int u = 0; u < 8; ++u) idx[u] = cs[j + u];
        float f[8];
#pragma unroll
        for (int u = 0; u < 8; ++u) f[u] = feat[(size_t)idx[u] * HID + lane];
        acc += ((f[0] + f[1]) + (f[2] + f[3])) + ((f[4] + f[5]) + (f[6] + f[7]));
    }
    for (; j < len; ++j) acc += feat[(size_t)cs[j] * HID + lane];
    return acc;
}

// conv1 aggregation + relu + fused W2 GEMM
__launch_bounds__(256)
__global__ void k_agg1(const float* __restrict__ hs, const int* __restrict__ csr,
                       const int* __restrict__ rows, const float* __restrict__ b1,
                       const float* __restrict__ W2, float* __restrict__ hs2) {
    __shared__ float w2[HID * HID];
    __shared__ float h1s[8][HID];
    for (int i = threadIdx.x; i < HID * HID; i += 256) w2[i] = W2[i];
    int lane = threadIdx.x & 31, hw = threadIdx.x >> 5;
    int node = blockIdx.x * 8 + hw;
    int r0 = rows[node], r1 = rows[node + 1];
    float dv = rsqrtf((float)(r1 - r0 + 1));
    float acc = hs[(size_t)node * HID + lane];      // self loop
    acc = gather_row(hs, csr + r0, r1 - r0, lane, acc);
    h1s[hw][lane] = fmaxf(acc * dv + b1[lane], 0.f);
    __syncthreads();
    float g = 0.f;
#pragma unroll
    for (int k = 0; k < HID; ++k) g += h1s[hw][k] * w2[k * HID + lane];
    hs2[(size_t)node * HID + lane] = g * dv;
}

// conv2 aggregation + relu + fused MLP head
__launch_bounds__(256)
__global__ void k_agg2(const float* __restrict__ hs2, const int* __restrict__ csr,
                       const int* __restrict__ rows, const float* __restrict__ b2,
                       const float* __restrict__ Wl1, const float* __restrict__ bl1,
                       const float* __restrict__ Wl2, const float* __restrict__ bl2,
                       float* __restrict__ out) {
    __shared__ float wl1[HID * HID];
    __shared__ float h2s[8][HID];
    for (int i = threadIdx.x; i < HID * HID; i += 256) wl1[i] = Wl1[i];
    int lane = threadIdx.x & 31, hw = threadIdx.x >> 5;
    int node = blockIdx.x * 8 + hw;
    int r0 = rows[node], r1 = rows[node + 1];
    float dv = rsqrtf((float)(r1 - r0 + 1));
    float acc = hs2[(size_t)node * HID + lane];
    acc = gather_row(hs2, csr + r0, r1 - r0, lane, acc);
    float h2 = fmaxf(acc * dv + b2[lane], 0.f);
    h2s[hw][lane] = h2;
    __syncthreads();
    float g = bl1[lane];
#pragma unroll
    for (int k = 0; k < HID; ++k) g += h2s[hw][k] * wl1[k * HID + lane];
    float o = fmaxf(g, 0.f) * Wl2[lane];
#pragma unroll
    for (int off = 16; off; off >>= 1) o += __shfl_down(o, off, 32);
    if (lane == 0) out[node] = o + *bl2;
}

extern "C" void kernel_launch(void* const* d_in, const int* in_sizes, int n_in,
                              void* d_out, int out_size, void* d_ws, size_t ws_size,
                              hipStream_t stream) {
    const float* x   = (const float*)d_in[0];
    const int*   e   = (const int*)d_in[1];
    const float* W1  = (const float*)d_in[2];
    const float* b1  = (const float*)d_in[3];
    const float* W2  = (const float*)d_in[4];
    const float* b2  = (const float*)d_in[5];
    const float* Wl1 = (const float*)d_in[6];
    const float* bl1 = (const float*)d_in[7];
    const float* Wl2 = (const float*)d_in[8];
    const float* bl2 = (const float*)d_in[9];
    float* out = (float*)d_out;

    char* w = (char*)d_ws;
    unsigned int*   ebuf    = (unsigned int*)(w + O_EBUF);
    float*          hs      = (float*)(w + O_HS);
    float*          hs2     = (float*)(w + O_HS2);
    int*            ghist   = (int*)(w + O_GH);
    unsigned short* gh2     = (unsigned short*)(w + O_GH);   // overlays ghist (dead)
    int*            cursors = (int*)(w + O_CUR);
    int*            csr     = (int*)(w + O_CSR);             // overlays cursors (dead)
    int*            rows    = (int*)(w + O_ROWS);
    int*            bstart  = (int*)(w + O_BST);
    int*            btot    = (int*)(w + O_BTOT);
    int*            flag    = (int*)(w + O_FLAG);

    const int NB_NODE = N_NODES / 8;          // 12500 exact

    k_detect<<<1, 256, 0, stream>>>((const unsigned int*)e, flag);
    k_hist<<<NBLK, 256, 0, stream>>>(e, flag, ghist);
    k_scan1<<<NBKT, 64, 0, stream>>>(ghist, btot);
    k_scan2<<<1, 1024, 0, stream>>>(btot, bstart);
    k_scan3<<<1, 256, 0, stream>>>(ghist, bstart, cursors);
    k_scatter<<<NBLK, 512, 0, stream>>>(e, flag, ghist, cursors, ebuf);
    k_sort2a<<<NBKT * 4, 512, 0, stream>>>(ebuf, bstart, gh2);
    k_sort2b<<<NBKT * 4, 512, 0, stream>>>(ebuf, bstart, gh2, csr, rows);

    k_gemm1<<<NB_NODE, 256, 0, stream>>>(x, W1, rows, hs);
    k_agg1<<<NB_NODE, 256, 0, stream>>>(hs, csr, rows, b1, W2, hs2);
    k_agg2<<<NB_NODE, 256, 0, stream>>>(hs2, csr, rows, b2,
                                        Wl1, bl1, Wl2, bl2, out);
}